// Round 4
// baseline (291.786 us; speedup 1.0000x reference)
//
#include <hip/hip_runtime.h>
#include <cstdint>

// Problem constants (from reference setup_inputs): B=256, IN=1024, OUT=1024.
#define BATCH 256
#define INF   1024
#define OUTF  1024

// ---------------------------------------------------------------------------
// Decode pulses [n][32] (floats 0./1., index 0 = MSB) -> f32 values [n].
// Coalesced: each thread reads its own contiguous 128 B (8x float4).
// ---------------------------------------------------------------------------
__device__ __forceinline__ uint32_t assemble_bits(const float4* __restrict__ p4) {
    uint32_t u = 0;
#pragma unroll
    for (int j = 0; j < 8; ++j) {
        float4 v = p4[j];
        int sh = 31 - j * 4;  // pulse index j*4 -> bit (31 - j*4)
        u |= (v.x > 0.5f ? 1u : 0u) << sh;
        u |= (v.y > 0.5f ? 1u : 0u) << (sh - 1);
        u |= (v.z > 0.5f ? 1u : 0u) << (sh - 2);
        u |= (v.w > 0.5f ? 1u : 0u) << (sh - 3);
    }
    return u;
}

__global__ __launch_bounds__(256) void decode_pulses(
    const float* __restrict__ pulses, float* __restrict__ out, int n) {
    int i = blockIdx.x * blockDim.x + threadIdx.x;
    if (i >= n) return;
    const float4* p4 = reinterpret_cast<const float4*>(pulses) + (size_t)i * 8;
    out[i] = __uint_as_float(assemble_bits(p4));
}

// Decode w pulses [OUT][IN][32] -> transposed wT[IN][OUT] so that the GEMM's
// inner-loop load wT[k][o] is coalesced across lanes (o contiguous).
__global__ __launch_bounds__(256) void decode_pulses_wT(
    const float* __restrict__ pulses, float* __restrict__ wT) {
    int i = blockIdx.x * blockDim.x + threadIdx.x;  // over OUT*IN, row-major [o][k]
    int o = i >> 10;        // / INF
    int k = i & (INF - 1);  // % INF
    const float4* p4 = reinterpret_cast<const float4*>(pulses) + (size_t)i * 8;
    wT[(size_t)k * OUTF + o] = __uint_as_float(assemble_bits(p4));
}

// ---------------------------------------------------------------------------
// GEMM with strict left-to-right FP32 accumulation + pulse re-encode.
// Block (64,4): o = bx*64+tx (lane-contiguous), b = by*4+ty (wave-uniform).
// fp contract(off): hipcc defaults to -ffp-contract=fast-honor-pragmas, which
// would fuse mul+add into v_fmac_f32 (skips product rounding) and break
// bit-exactness vs the reference's round(mul) -> round(add) sequence.
// ---------------------------------------------------------------------------
__global__ __launch_bounds__(256) void gemm_encode(
    const float* __restrict__ xf,   // [BATCH][INF]
    const float* __restrict__ wT,   // [INF][OUTF]
    float* __restrict__ out)        // [BATCH][OUTF][32]
{
#pragma clang fp contract(off)
    int o = blockIdx.x * 64 + threadIdx.x;
    int b = blockIdx.y * 4 + threadIdx.y;

    const float* __restrict__ xrow = xf + (size_t)b * INF;
    const float* __restrict__ wcol = wT + o;

    float acc = 0.0f;
    for (int k = 0; k < INF; ++k) {
        float p = xrow[k] * wcol[(size_t)k * OUTF];  // rounded to f32
        acc = acc + p;                               // strictly sequential add
    }

    uint32_t u = __float_as_uint(acc);
    float4* dst = reinterpret_cast<float4*>(out) + ((size_t)b * OUTF + o) * 8;
#pragma unroll
    for (int j = 0; j < 8; ++j) {
        int sh = 31 - j * 4;
        dst[j] = make_float4((float)((u >> sh) & 1u),
                             (float)((u >> (sh - 1)) & 1u),
                             (float)((u >> (sh - 2)) & 1u),
                             (float)((u >> (sh - 3)) & 1u));
    }
}

extern "C" void kernel_launch(void* const* d_in, const int* in_sizes, int n_in,
                              void* d_out, int out_size, void* d_ws, size_t ws_size,
                              hipStream_t stream) {
    const float* x_pulses = (const float*)d_in[0];   // [256][1024][32]
    const float* w_pulses = (const float*)d_in[1];   // [1024][1024][32]
    float* out = (float*)d_out;                      // [256][1024][32]

    float* xf = (float*)d_ws;                        // 256*1024 floats  (1 MB)
    float* wT = xf + (size_t)BATCH * INF;            // 1024*1024 floats (4 MB)

    // 1) decode x -> xf
    {
        int n = BATCH * INF;                         // 262144
        decode_pulses<<<(n + 255) / 256, 256, 0, stream>>>(x_pulses, xf, n);
    }
    // 2) decode w -> wT (transposed)
    {
        int n = OUTF * INF;                          // 1048576
        decode_pulses_wT<<<n / 256, 256, 0, stream>>>(w_pulses, wT);
    }
    // 3) GEMM + encode
    {
        dim3 grid(OUTF / 64, BATCH / 4);             // (16, 64)
        dim3 block(64, 4);
        gemm_encode<<<grid, block, 0, stream>>>(xf, wT, out);
    }
}